// Round 13
// baseline (74.740 us; speedup 1.0000x reference)
//
#include <hip/hip_runtime.h>

// GPDGaussian: per-pixel 629x3 conv -> (m, S=R^T diag(s) R, s)
// r13 ROW-PAIR PACKING: thread T = (px = T/17, u = T%17) owns ROWS (2u,2u+1)
// of ONE pixel, packed in f32x2. 7 px per 128-thread block: 119/128 = 93%
// lane util in phases B/C (r12: 80%, and each cs cell read served only 2 px).
// Rotation arithmetic is bit-identical per pixel; only thread mapping changed.
// Bonus: cvt_pkrtz(R[2u][n],R[2u+1][n]) IS the V dword (f16 row-pair layout),
// and each thread's S output is 68 contiguous floats (17 aligned float4).

#define CCH 34
#define ACH 561
#define HWPIX 4096
#define NPIX 16384
#define PXB 7                   // pixels per block
#define NTHR 128
#define CLEN 141                // max angles per chunk (141,140,140,140)
#define CSPX (CLEN * 8)         // cs bytes per px per chunk = 1128
#define VROW 36                 // dwords per V row-pair (144B)
#define VPX (17 * VROW * 4)     // 2448 B per-pixel V region
#define OFF_S 557056
#define OFF_s 19496960
#define LOG2E 1.4426950408889634f

typedef float    f32x2 __attribute__((ext_vector_type(2)));
typedef _Float16 h2    __attribute__((ext_vector_type(2)));

struct Pairs {
    short i[ACH]; short j[ACH];
    constexpr Pairs() : i(), j() {
        int p = 0;
        for (int a = 0; a < CCH - 1; ++a)
            for (int b = a + 1; b < CCH; ++b) { i[p] = (short)a; j[p] = (short)b; ++p; }
    }
};
__device__ constexpr Pairs PR{};

__device__ __forceinline__ float dot2h(h2 a, h2 b, float c) {
#if __has_builtin(__builtin_amdgcn_fdot2)
    return __builtin_amdgcn_fdot2(a, b, c, false);
#else
    return fmaf((float)a[0], (float)b[0], fmaf((float)a[1], (float)b[1], c));
#endif
}

// Givens rotation on packed row-pairs: Ri' = c*Ri + s*Rj ; Rj' = c*Rj - s*Ri
__device__ __forceinline__ void rot2(f32x2& Ri, f32x2& Rj, f32x2 c2, f32x2 s2) {
    f32x2 t1 = s2 * Rj;
    f32x2 t2 = s2 * Ri;
    Ri = __builtin_elementwise_fma(c2, Ri, t1);
    Rj = __builtin_elementwise_fma(c2, Rj, -t2);
}

template <int P0, int P1>
__device__ __forceinline__ void apply_rots(f32x2* R2, const char* csb) {
    #pragma unroll
    for (int k = P0; k < P1; ++k) {
        f32x2 cell = *(const f32x2*)(csb + (k - P0) * 8);   // {c,s}, b64 read
        f32x2 c2 = __builtin_shufflevector(cell, cell, 0, 0);
        f32x2 s2 = __builtin_shufflevector(cell, cell, 1, 1);
        rot2(R2[PR.i[k]], R2[PR.j[k]], c2, s2);
    }
}

__device__ __forceinline__ float2 cs_of(float wv) {
    // angle = pi*tanh(wv); HW cos/sin take revolutions: tanh(wv)/2
    float e  = __builtin_amdgcn_exp2f((2.0f * LOG2E) * wv);
    float tt = 1.0f - 2.0f * __builtin_amdgcn_rcpf(e + 1.0f);
    float rv = 0.5f * tt;
    return make_float2(__builtin_amdgcn_cosf(rv), __builtin_amdgcn_sinf(rv));
}

// one task = one pixel's angle l -> 8B {c,s} write
template <int G0, int LEN>
__device__ __forceinline__ void fill_cs(const float* __restrict__ Wm,
                                        const float* __restrict__ bvec,
                                        const float* xs, char* csbuf,
                                        int npx, int t) {
    for (int o = t; o < npx * LEN; o += NTHR) {
        int px = (int)((unsigned)o / (unsigned)LEN);
        int l  = o - px * LEN;
        int ch = 2 * CCH + G0 + l;
        float wv = fmaf(Wm[ch*3+0], xs[px*3+0],
                   fmaf(Wm[ch*3+1], xs[px*3+1], Wm[ch*3+2] * xs[px*3+2])) + bvec[ch];
        *(float2*)(csbuf + px * CSPX + l * 8) = cs_of(wv);
    }
}

__global__ __launch_bounds__(NTHR, 4) void gpd_kernel(
    const float* __restrict__ x,     // (4,3,64,64)
    const float* __restrict__ Wm,    // (629,3)
    const float* __restrict__ bvec,  // (629,)
    float* __restrict__ out)
{
    __shared__ alignas(16) char vbuf[PXB * VPX];   // 17136 B (cs 7896 overlays)
    __shared__ _Float16 lds_sh[PXB * CCH];         // s in f16
    __shared__ float xs[PXB * 3];

    const int t   = threadIdx.x;
    const int p0  = blockIdx.x * PXB;
    const int npx = min(PXB, NPIX - p0);

    // ---- stage x into LDS ----
    for (int i = t; i < npx * 3; i += NTHR) {
        int px = (int)((unsigned)i / 3u); int c = i - px * 3;
        int p = p0 + px; int b = p >> 12; int hw = p & 4095;
        xs[i] = x[(b * 3 + c) * HWPIX + hw];
    }
    __syncthreads();

    // ---- A: mean + s channels ----
    for (int o = t; o < npx * 68; o += NTHR) {
        int q = (int)((unsigned)o / 68u); int ch = o - q * 68;
        int p = p0 + q; int b = p >> 12; int hw = p & 4095;
        float wv = fmaf(Wm[ch*3+0], xs[q*3+0],
                   fmaf(Wm[ch*3+1], xs[q*3+1], Wm[ch*3+2] * xs[q*3+2])) + bvec[ch];
        if (ch < CCH) {
            out[(size_t)p * CCH + ch] = wv;                       // mean
        } else {
            float e  = __builtin_amdgcn_exp2f(-wv * LOG2E);
            float sg = __builtin_amdgcn_rcpf(1.0f + e);
            float sv = fmaf(999.999f, sg, 0.001f);                // s
            int c = ch - CCH;
            out[OFF_s + (size_t)(b * CCH + c) * HWPIX + hw] = sv;
            lds_sh[q * CCH + c] = (_Float16)sv;
        }
    }

    const int px = t / 17;                   // pixel owned by this thread
    const int u  = t - px * 17;              // row-pair index: rows (2u, 2u+1)
    const bool act = (px < npx);
    const char* csb = vbuf + px * CSPX;      // this pixel's cs region

    f32x2 R2[CCH];                           // R2[n] = {R[2u][n], R[2u+1][n]}
    #pragma unroll
    for (int n = 0; n < CCH; ++n) {
        R2[n][0] = (n == 2 * u)     ? 1.0f : 0.0f;
        R2[n][1] = (n == 2 * u + 1) ? 1.0f : 0.0f;
    }

    // ---- 4 chunks: fill cos/sin -> rotate ----
    fill_cs<0, 141>(Wm, bvec, xs, vbuf, npx, t);
    __syncthreads();
    if (act) apply_rots<0, 141>(R2, csb);
    __syncthreads();
    fill_cs<141, 140>(Wm, bvec, xs, vbuf, npx, t);
    __syncthreads();
    if (act) apply_rots<141, 281>(R2, csb);
    __syncthreads();
    fill_cs<281, 140>(Wm, bvec, xs, vbuf, npx, t);
    __syncthreads();
    if (act) apply_rots<281, 421>(R2, csb);
    __syncthreads();
    fill_cs<421, 140>(Wm, bvec, xs, vbuf, npx, t);
    __syncthreads();
    if (act) apply_rots<421, 561>(R2, csb);
    __syncthreads();                         // all cs reads done; V overlays

    // ---- V write: cvt_pkrtz(R2[n]) IS the f16 row-pair dword [u][n] ----
    if (act) {
        unsigned* vb = (unsigned*)(vbuf + px * VPX) + u * VROW;
        #pragma unroll
        for (int n = 0; n < CCH; ++n)
            vb[n] = __builtin_bit_cast(unsigned,
                        __builtin_amdgcn_cvt_pkrtz(R2[n][0], R2[n][1]));
    }
    __syncthreads();

    // ---- phase C: S rows 2u and 2u+1 in ONE pass (shared rr reads) ----
    if (act) {
        const unsigned* vb = (const unsigned*)(vbuf + px * VPX);
        const _Float16* sh = lds_sh + px * CCH;
        float aL[CCH], aH[CCH];
        #pragma unroll
        for (int n = 0; n < CCH; ++n) { aL[n] = 0.0f; aH[n] = 0.0f; }
        for (int mp = 0; mp < 17; ++mp) {
            const unsigned* row = vb + mp * VROW;
            h2 sh2 = *(const h2*)(sh + 2 * mp);
            h2 vkL = __builtin_bit_cast(h2, row[2 * u])     * sh2;
            h2 vkH = __builtin_bit_cast(h2, row[2 * u + 1]) * sh2;
            #pragma unroll
            for (int g = 0; g < 8; ++g) {
                uint4 rr = *(const uint4*)(row + 4 * g);
                h2 r0 = __builtin_bit_cast(h2, rr.x), r1 = __builtin_bit_cast(h2, rr.y);
                h2 r2 = __builtin_bit_cast(h2, rr.z), r3 = __builtin_bit_cast(h2, rr.w);
                aL[4*g+0] = dot2h(vkL, r0, aL[4*g+0]);  aH[4*g+0] = dot2h(vkH, r0, aH[4*g+0]);
                aL[4*g+1] = dot2h(vkL, r1, aL[4*g+1]);  aH[4*g+1] = dot2h(vkH, r1, aH[4*g+1]);
                aL[4*g+2] = dot2h(vkL, r2, aL[4*g+2]);  aH[4*g+2] = dot2h(vkH, r2, aH[4*g+2]);
                aL[4*g+3] = dot2h(vkL, r3, aL[4*g+3]);  aH[4*g+3] = dot2h(vkH, r3, aH[4*g+3]);
            }
            uint2 rr2 = *(const uint2*)(row + 32);
            h2 r32 = __builtin_bit_cast(h2, rr2.x), r33 = __builtin_bit_cast(h2, rr2.y);
            aL[32] = dot2h(vkL, r32, aL[32]);  aH[32] = dot2h(vkH, r32, aH[32]);
            aL[33] = dot2h(vkL, r33, aL[33]);  aH[33] = dot2h(vkH, r33, aH[33]);
        }
        // write rows 2u,2u+1 = 68 contiguous floats = 17 aligned float4
        float* os = out + OFF_S + (size_t)(p0 + px) * (CCH * CCH) + 2 * u * CCH;
        #pragma unroll
        for (int q = 0; q < 17; ++q) {
            float4 v;
            v.x = (4*q+0 < 34) ? aL[4*q+0] : aH[4*q+0-34];
            v.y = (4*q+1 < 34) ? aL[4*q+1] : aH[4*q+1-34];
            v.z = (4*q+2 < 34) ? aL[4*q+2] : aH[4*q+2-34];
            v.w = (4*q+3 < 34) ? aL[4*q+3] : aH[4*q+3-34];
            *(float4*)(os + 4 * q) = v;
        }
    }
}

extern "C" void kernel_launch(void* const* d_in, const int* in_sizes, int n_in,
                              void* d_out, int out_size, void* d_ws, size_t ws_size,
                              hipStream_t stream) {
    const float* x  = (const float*)d_in[0];
    const float* W  = (const float*)d_in[1];
    const float* bv = (const float*)d_in[2];
    float* out = (float*)d_out;
    const int nblk = (NPIX + PXB - 1) / PXB;   // 2341
    hipLaunchKernelGGL(gpd_kernel, dim3(nblk), dim3(NTHR), 0, stream,
                       x, W, bv, out);
}